// Round 3
// baseline (73.370 us; speedup 1.0000x reference)
//
#include <hip/hip_runtime.h>
#include <math.h>

// Problem constants (match reference)
#define NF 256          // features
#define NB 64           // batch
#define M_CON 515       // 2N+3 constraints
static constexpr double EPS_Q  = 1e-4;
static constexpr double SIGMA  = 0.1;
static constexpr double CAPC   = 10.0;
static constexpr int    ITERS  = 20;
// Early-exit: musum < 1e-9 => mu ~ 2e-12; remaining Newton steps move x by
// <~1e-8 (worst-case amplification 1/EPS_Q), invisible in the fp32 output
// and far below the existing ~1.5e-7 rcp-noise floor.
static constexpr double MU_EXIT = 1e-9;

// Fast fp64 reciprocal: v_rcp_f64 seed + 1 NR step -> ~fp64 noise floor.
__device__ __forceinline__ double drcp(double x) {
    double r = __builtin_amdgcn_rcp(x);
    r = fma(r, fma(-x, r, 1.0), r);
    return r;
}
// Raw rcp (~2^-26 rel): ONLY for step-ratio denominators and alpha.
__device__ __forceinline__ double drcp_fast(double x) {
    return __builtin_amdgcn_rcp(x);
}

// DPP cross-lane for fp64: two 32-bit v_mov_b32 dpp + reassemble.
template <int CTRL>
__device__ __forceinline__ double dpp_d(double v) {
    const int lo = __builtin_amdgcn_update_dpp(0, __double2loint(v), CTRL, 0xF, 0xF, true);
    const int hi = __builtin_amdgcn_update_dpp(0, __double2hiint(v), CTRL, 0xF, 0xF, true);
    return __hiloint2double(hi, lo);
}
// Wave sum/max: result valid in LANE 63 ONLY (lane 63 ships it to LDS).
__device__ __forceinline__ double wave_sum_l63(double v) {
    v += dpp_d<0x121>(v);   // row_ror:1
    v += dpp_d<0x122>(v);   // row_ror:2
    v += dpp_d<0x124>(v);   // row_ror:4
    v += dpp_d<0x128>(v);   // row_ror:8
    v += dpp_d<0x142>(v);   // row_bcast15
    v += dpp_d<0x143>(v);   // row_bcast31
    return v;
}
__device__ __forceinline__ double wave_max_nn_l63(double v) {
    v = fmax(v, dpp_d<0x121>(v));
    v = fmax(v, dpp_d<0x122>(v));
    v = fmax(v, dpp_d<0x124>(v));
    v = fmax(v, dpp_d<0x128>(v));
    v = fmax(v, dpp_d<0x142>(v));
    v = fmax(v, dpp_d<0x143>(v));
    return v;
}

struct dbl2 { double x, y; };

// ONE item per BLOCK, 4 waves, 1 feature per lane. Wall time == one block's
// serial 20-iter chain (all 64 blocks concurrent on 256 CUs). Round-2
// post-mortem: kernel is critical-path-bound; the two sync points cost
// ~500-700 cyc each. Round-3 changes:
//  * early-exit on musum < 1e-9 (uniform, identical in all waves);
//  * scalar-constraint ratios folded into rmax_p BEFORE the DPP tree
//    (fmax commutative -> bit-identical, removes 6-deep chain post-sync2);
//  * ratio-only z-reciprocals hoisted into group 1's latency shadow;
//  * LDS [wave][quantity] layout: lane63 writes b128s, combine reads are
//    b128 broadcast loads issued right after the barrier; combine order
//    (r0+r1)+(r2+r3) preserved -> bit-exact.
__global__ __launch_bounds__(256, 1)
void pdipm_kernel(const float* __restrict__ xin,
                  const int* __restrict__ male,
                  float* __restrict__ out) {
    const int b = blockIdx.x;
    const int tid = threadIdx.x;      // == feature index (0..255)
    const int lane = tid & 63;
    const int w = tid >> 6;

    __shared__ __align__(16) double red1[4][4];  // [wave][q] : s11,s12,t1,t2
    __shared__ __align__(16) double red2[4][2];  // [wave][q] : Sdsdz, rmax

    const double mf = (double)male[tid];
    double e = (double)xin[b * NF + tid];   // e = -(EPS*x+p), x=0 -> e = -p = xin
    double x = 0.0;
    double s_lo = 1.0, s_hi = 1.0, z_lo = 1.0, z_hi = 1.0;
    double rs_l = 1.0;                       // rs_lo scalar (s - x = 1)

    // one-time: nm = sum(mf) over all 256 features
    {
        const double v = wave_sum_l63(mf);
        if (lane == 63) red1[w][0] = v;
    }
    __syncthreads();
    const double nm = (red1[0][0] + red1[1][0]) + (red1[2][0] + red1[3][0]);
    __syncthreads();                          // protect red1 before iter-0 writes
    const double rhs_fair = CAPC * nm * (1.0 / 256.0);

    // Scalar-constraint state (wave-uniform).
    double s0 = 1.0, z0 = 1.0, sA = 1.0, zA = 1.0, sB = 1.0, zB = 1.0;
    double rs0 = 1.0 - CAPC;                  // s0 + 0 - C
    double rsA = -rhs_fair;                   // 1 + 0 - (rhs_fair+1)
    double rsB = 1.0 + rhs_fair;              // 1 - 0 + rhs_fair
    double musum = (double)M_CON;             // all s=z=1

    for (int it = 0; it < ITERS; ++it) {
        const double smu = SIGMA * musum * (1.0 / (double)M_CON);

        // ---- wave-uniform scalar precompute (overlaps group1) ----
        const double i_s0 = drcp(s0), i_sA = drcp(sA), i_sB = drcp(sB);
        const double i_z0 = drcp_fast(z0), i_zA = drcp_fast(zA), i_zB = drcp_fast(zB);
        const double d0 = z0 * i_s0, dA = zA * i_sA, dB = zB * i_sB;
        const double beta  = d0 * rs0 + smu * i_s0;
        const double gamma = (dA * rsA + smu * i_sA) - (dB * rsB + smu * i_sB);
        const double ia  = drcp(d0);
        const double ibb = drcp(dA + dB);

        // ---- group 1: per-feature (1 feature/lane) ----
        const double i_slo = drcp(s_lo);
        const double i_shi = drcp(s_hi);
        const double i_zlo = drcp_fast(z_lo);   // ratio-only; hoisted for overlap
        const double i_zhi = drcp_fast(z_hi);
        const double d_lo = z_lo * i_slo;
        const double d_hi = z_hi * i_shi;
        const double invD = drcp(EPS_Q + d_lo + d_hi);
        const double rhat = e + d_lo * rs_l + smu * (i_slo - i_shi);
        const double y = rhat * invD;

        // 4 reductions: wave DPP tree -> lane63 -> LDS -> 4-term combine
        const double p0 = wave_sum_l63(invD);
        const double p1 = wave_sum_l63(mf * invD);
        const double p2 = wave_sum_l63(y);
        const double p3 = wave_sum_l63(mf * y);
        if (lane == 63) {
            *reinterpret_cast<dbl2*>(&red1[w][0]) = dbl2{p0, p1};
            *reinterpret_cast<dbl2*>(&red1[w][2]) = dbl2{p2, p3};
        }
        __syncthreads();
        // b128 broadcast reads first, then combine (order (r0+r1)+(r2+r3)).
        const dbl2 a0 = *reinterpret_cast<const dbl2*>(&red1[0][0]);
        const dbl2 a1 = *reinterpret_cast<const dbl2*>(&red1[1][0]);
        const dbl2 a2 = *reinterpret_cast<const dbl2*>(&red1[2][0]);
        const dbl2 a3 = *reinterpret_cast<const dbl2*>(&red1[3][0]);
        const dbl2 c0 = *reinterpret_cast<const dbl2*>(&red1[0][2]);
        const dbl2 c1_ = *reinterpret_cast<const dbl2*>(&red1[1][2]);
        const dbl2 c2_ = *reinterpret_cast<const dbl2*>(&red1[2][2]);
        const dbl2 c3 = *reinterpret_cast<const dbl2*>(&red1[3][2]);
        const double s11 = (a0.x + a1.x) + (a2.x + a3.x);
        const double s12 = (a0.y + a1.y) + (a2.y + a3.y);
        const double t1  = (c0.x + c1_.x) + (c2_.x + c3.x);
        const double t2  = (c0.y + c1_.y) + (c2_.y + c3.y);

        // ---- 2x2 capacitance algebra (closed-form M^-1 1 / M^-1 m) ----
        const double k11 = ia + s11;
        const double k22 = ibb + s12;
        const double i_det = drcp(k11 * k22 - s12 * s12);
        const double c1 = (k22 * t1 - s12 * t2) * i_det;
        const double c2 = (k11 * t2 - s12 * t1) * i_det;
        const double a1c =  ia * k22 * i_det;
        const double a2c = -ia * s12 * i_det;
        const double b1c = -ibb * s12 * i_det;
        const double b2c =  ibb * k11 * i_det;
        const double C1 = c1 + beta * a1c + gamma * b1c;
        const double C2 = c2 + beta * a2c + gamma * b2c;
        const double C1pC2 = C1 + C2;

        // ---- Sdx/Smdx via identities (no reduction) ----
        const double Sdx  = t1 - C1 * s11 - C2 * s12;
        const double Smdx = t2 - C1pC2 * s12;
        const double ds0 = -rs0 - Sdx;
        const double dsA = -rsA - Smdx;
        const double dsB = -rsB + Smdx;
        const double dz0 = smu * i_s0 - z0 - d0 * ds0;
        const double dzA = smu * i_sA - zA - dA * dsA;
        const double dzB = smu * i_sB - zB - dB * dsB;

        // ---- group 2: per-feature directions ----
        const double C12 = (mf != 0.0) ? C1pC2 : C1;
        const double dx = fma(-invD, C12, y);
        const double ds_lo = dx - rs_l;            // ds = -rs - G dx, (G dx)_lo = -dx
        const double ds_hi = -dx;                  // rs_hi == 0 exactly
        const double dz_lo = smu * i_slo - z_lo - d_lo * ds_lo;
        const double dz_hi = smu * i_shi - z_hi - d_hi * ds_hi;
        const double dsdz_p = ds_lo * dz_lo + ds_hi * dz_hi;
        const double q1 = -ds_lo * i_slo;
        const double q2 = -ds_hi * i_shi;
        const double q3 = -dz_lo * i_zlo;
        const double q4 = -dz_hi * i_zhi;
        double rmax_p = fmax(0.0, fmax(fmax(q1, q2), fmax(q3, q4)));
        // Fold wave-uniform scalar ratios in BEFORE the tree (fmax exact,
        // commutative -> same global max, shorter post-sync chain).
        rmax_p = fmax(rmax_p, fmax(-ds0 * i_s0, -dz0 * i_z0));
        rmax_p = fmax(rmax_p, fmax(-dsA * i_sA, -dzA * i_zA));
        rmax_p = fmax(rmax_p, fmax(-dsB * i_sB, -dzB * i_zB));

        const double pp0 = wave_sum_l63(dsdz_p);
        const double pp1 = wave_max_nn_l63(rmax_p);
        if (lane == 63) {
            *reinterpret_cast<dbl2*>(&red2[w][0]) = dbl2{pp0, pp1};
        }
        __syncthreads();
        const dbl2 r0 = *reinterpret_cast<const dbl2*>(&red2[0][0]);
        const dbl2 r1 = *reinterpret_cast<const dbl2*>(&red2[1][0]);
        const dbl2 r2 = *reinterpret_cast<const dbl2*>(&red2[2][0]);
        const dbl2 r3 = *reinterpret_cast<const dbl2*>(&red2[3][0]);
        const double Sdsdz_w = (r0.x + r1.x) + (r2.x + r3.x);
        const double rmax = fmax(fmax(r0.y, r1.y), fmax(r2.y, r3.y));
        const double Sdsdz = Sdsdz_w + ds0 * dz0 + dsA * dzA + dsB * dzB;

        const double alpha = fmin(1.0, 0.99 * drcp_fast(fmax(rmax, 0.99)));
        const double omA = 1.0 - alpha;

        // ---- state update (identities keep rs/musum exact) ----
        const double adx = alpha * dx;
        x += adx;
        e = fma(-EPS_Q, adx, e);
        s_lo = fma(alpha, ds_lo, s_lo);
        s_hi = fma(alpha, ds_hi, s_hi);
        z_lo = fma(alpha, dz_lo, z_lo);
        z_hi = fma(alpha, dz_hi, z_hi);
        rs_l *= omA;

        s0 = fma(alpha, ds0, s0); z0 = fma(alpha, dz0, z0);
        sA = fma(alpha, dsA, sA); zA = fma(alpha, dzA, zA);
        sB = fma(alpha, dsB, sB); zB = fma(alpha, dzB, zB);
        rs0 *= omA; rsA *= omA; rsB *= omA;
        musum = musum * (1.0 - alpha * (1.0 - SIGMA)) + alpha * alpha * Sdsdz;

        // Converged: remaining steps move x below fp32 resolution.
        if (musum < MU_EXIT) break;
    }

    out[b * NF + tid] = (float)x;
}

extern "C" void kernel_launch(void* const* d_in, const int* in_sizes, int n_in,
                              void* d_out, int out_size, void* d_ws, size_t ws_size,
                              hipStream_t stream) {
    const float* xin  = (const float*)d_in[0];   // [64, 256] fp32
    const int*   male = (const int*)d_in[1];     // [256] int32
    float* out = (float*)d_out;                  // [64, 256] fp32
    pdipm_kernel<<<NB, 256, 0, stream>>>(xin, male, out);
}